// Round 6
// baseline (55519.366 us; speedup 1.0000x reference)
//
#include <hip/hip_runtime.h>
#include <hip/hip_bf16.h>
#include <math.h>

// ---------------------------------------------------------------------------
// VQ-VAE forward, MI355X. Round 6: replicate the np reference's FP32 rounding
// in the VQ distance computation. d2 = fl32( fl32(zz - 2*dot) + ee ) with
// zz ~ 36 dominating => argmin depends on the fp32 rounding grid (ulp~3.8e-6),
// not the true distances. R3 (fp32, no zz) and R5 (fp64, no zz) gave BIT-
// IDENTICAL absmax 0.3496094 => discrete argmin mismatches vs np, robust to
// my precision => must mimic np's arithmetic, not improve on it.
//   zz : numpy-pairwise fp32 sum of z32^2 (8-accumulator pattern, n=64)
//   dot: exact (fp64) then rounded to fp32 (within ~4ulp of any BLAS sgemm)
//   d2 : __fsub_rn/__fadd_rn sequence (no contraction/reassociation)
//   q  : emb rows; decoder input e_st = fl32(fl32(q - z32) + z32)
// Encoder stays fp64 (z = correctly-rounded truth), decoder fp32.
// Workspace high-water: 16384 + 160 MiB (R5-proven; GB_S1=16384 fix retained).
// ---------------------------------------------------------------------------

#define NPOS   262144    // 64*64*64 z positions
#define OUTPIX 12582912  // 64*3*256*256

// block (256 thr) fp64 sum/sumsq reduce -> fp64 atomics.
__device__ __forceinline__ void block_stats_atomic(double s, double q,
                                                   double* sum_p, double* sq_p) {
  #pragma unroll
  for (int o = 32; o; o >>= 1) { s += __shfl_down(s, o, 64); q += __shfl_down(q, o, 64); }
  __shared__ double ls[4], lq[4];
  int lane = threadIdx.x & 63, wv = threadIdx.x >> 6;
  if (lane == 0) { ls[wv] = s; lq[wv] = q; }
  __syncthreads();
  if (threadIdx.x == 0) {
    atomicAdd(sum_p, ls[0] + ls[1] + ls[2] + ls[3]);
    atomicAdd(sq_p,  lq[0] + lq[1] + lq[2] + lq[3]);
  }
}

__global__ void k_zero(double* p) { if (threadIdx.x < 385) p[threadIdx.x] = 0.0; }

// numpy pairwise fp32 sum of 64 contiguous values (8 accumulators, then
// ((r0+r1)+(r2+r3)) + ((r4+r5)+(r6+r7))) — matches numpy's pairwise_sum n=64.
__device__ __forceinline__ float np_pairwise64(const float* sq) {
  float r[8];
  #pragma unroll
  for (int j = 0; j < 8; j++) r[j] = sq[j];
  #pragma unroll
  for (int i = 8; i < 64; i += 8)
    #pragma unroll
    for (int j = 0; j < 8; j++) r[j] = __fadd_rn(r[j], sq[i + j]);
  return __fadd_rn(__fadd_rn(__fadd_rn(r[0], r[1]), __fadd_rn(r[2], r[3])),
                   __fadd_rn(__fadd_rn(r[4], r[5]), __fadd_rn(r[6], r[7])));
}

// ee[e] = np-pairwise fp32 sum of emb[e,c]^2. <<<8,64>>>
__global__ void k_ee(const float* __restrict__ emb, float* __restrict__ ee) {
  int e = blockIdx.x * 64 + threadIdx.x;
  const float* p = emb + e * 64;
  float sq[64];
  #pragma unroll
  for (int c = 0; c < 64; c++) sq[c] = __fmul_rn(p[c], p[c]);
  ee[e] = np_pairwise64(sq);
}

// finalize BN (fp64): sc/sh per channel. <<<1,64>>>
__global__ void k_finalize_bn(const double* __restrict__ sums, const double* __restrict__ sqs,
                              const float* __restrict__ g, const float* __restrict__ bt,
                              double* __restrict__ sc, double* __restrict__ sh, double invN) {
  int c = threadIdx.x;
  double m = sums[c] * invN;
  double var = sqs[c] * invN - m * m;
  double s = (double)g[c] / sqrt(var + 1e-5);
  sc[c] = s;
  sh[c] = (double)bt[c] - m * s;
}

// conv1 core (fp64 acc): 3->64 k4 s2 p1, one output element
__device__ __forceinline__ double conv1_acc(const float* __restrict__ x, const float* wr,
                                            int b, int oh, int ow) {
  double acc = 0.0;
  int ih0 = oh * 2 - 1, iw0 = ow * 2 - 1;
  for (int ic = 0; ic < 3; ic++) {
    const float* ip = x + (((long)(b * 3 + ic)) << 16);
    #pragma unroll
    for (int kh = 0; kh < 4; kh++) {
      int ih = ih0 + kh;
      if ((unsigned)ih < 256u) {
        const float* rp = ip + (ih << 8);
        #pragma unroll
        for (int kw = 0; kw < 4; kw++) {
          int iw = iw0 + kw;
          if ((unsigned)iw < 256u)
            acc += (double)rp[iw] * (double)wr[(ic * 4 + kh) * 4 + kw];
        }
      }
    }
  }
  return acc;
}

// pass 1: BN1 stats only. grid = 64*64*128*128/256
__global__ __launch_bounds__(256) void k_conv1_stats(const float* __restrict__ x,
                                                     const float* __restrict__ w,
                                                     double* __restrict__ stats) {
  int idx = blockIdx.x * 256 + threadIdx.x;
  int ow = idx & 127, oh = (idx >> 7) & 127, oc = (idx >> 14) & 63, b = idx >> 20;
  float wr[48];
  const float* wp = w + oc * 48;
  #pragma unroll
  for (int i = 0; i < 48; i++) wr[i] = wp[i];
  double acc = conv1_acc(x, wr, b, oh, ow);
  block_stats_atomic(acc, acc * acc, &stats[oc], &stats[64 + oc]);
}

// pass 2 (per batch-sixteenth, 4 batches): conv1+BN1+ReLU -> A1s fp64. grid=16384
__global__ __launch_bounds__(256) void k_conv1_store(const float* __restrict__ x,
                                                     const float* __restrict__ w,
                                                     const double* __restrict__ sc,
                                                     const double* __restrict__ sh,
                                                     double* __restrict__ a1s, int boff) {
  int idx = blockIdx.x * 256 + threadIdx.x;
  int ow = idx & 127, oh = (idx >> 7) & 127, oc = (idx >> 14) & 63, b = (idx >> 20) + boff;
  float wr[48];
  const float* wp = w + oc * 48;
  #pragma unroll
  for (int i = 0; i < 48; i++) wr[i] = wp[i];
  double acc = conv1_acc(x, wr, b, oh, ow);
  double v = acc * sc[oc] + sh[oc];
  a1s[idx] = v > 0.0 ? v : 0.0;
}

// conv2 64->64 k4 s2 p1 (per sixteenth): A1s fp64 -> Z64, fused BN2 stats
__global__ __launch_bounds__(256) void k_conv2(const double* __restrict__ in,
                                               const float* __restrict__ w,
                                               double* __restrict__ out,
                                               double* __restrict__ sum_p, double* __restrict__ sq_p) {
  int idx = blockIdx.x * 256 + threadIdx.x;
  int ow = idx & 63, oh = (idx >> 6) & 63, oc = (idx >> 12) & 63, bl = idx >> 18;  // bl in [0,4)
  __shared__ double wl[1024];
  const float* wp = w + oc * 1024;
  for (int i = threadIdx.x; i < 1024; i += 256) wl[i] = (double)wp[i];
  __syncthreads();
  double acc = 0.0;
  int ih0 = oh * 2 - 1, iw0 = ow * 2 - 1;
  for (int ic = 0; ic < 64; ic++) {
    const double* ip = in + (((long)(bl * 64 + ic)) << 14);
    const double* wc = &wl[ic * 16];
    #pragma unroll
    for (int kh = 0; kh < 4; kh++) {
      int ih = ih0 + kh;
      if ((unsigned)ih < 128u) {
        const double* rp = ip + (ih << 7);
        #pragma unroll
        for (int kw = 0; kw < 4; kw++) {
          int iw = iw0 + kw;
          if ((unsigned)iw < 128u) acc += rp[iw] * wc[kh * 4 + kw];
        }
      }
    }
  }
  out[idx] = acc;
  block_stats_atomic(acc, acc * acc, &sum_p[oc], &sq_p[oc]);
}

// BN2 apply + ReLU in place on Z64. c=(idx>>12)&63
__global__ __launch_bounds__(256) void k_bn_apply(double* data, const double* __restrict__ sc,
                                                  const double* __restrict__ sh) {
  long idx = (long)blockIdx.x * 256 + threadIdx.x;
  int c = (int)((idx >> 12) & 63);
  double v = data[idx] * sc[c] + sh[c];
  data[idx] = v > 0.0 ? v : 0.0;
}

// encoder res 3x3 (fp64), per batch-quarter: T = conv3x3(relu(in)) + bias
__global__ __launch_bounds__(256) void k_res3x3_d(const double* __restrict__ in,
                                                  const float* __restrict__ w,
                                                  const float* __restrict__ bias,
                                                  double* __restrict__ t) {
  int idx = blockIdx.x * 256 + threadIdx.x;
  int ow = idx & 63, oh = (idx >> 6) & 63, oc = (idx >> 12) & 63, bl = idx >> 18; // [0,16)
  __shared__ double wl[576];
  const float* wp = w + oc * 576;
  for (int i = threadIdx.x; i < 576; i += 256) wl[i] = (double)wp[i];
  __syncthreads();
  double acc = (double)bias[oc];
  for (int ic = 0; ic < 64; ic++) {
    const double* ip = in + (((long)(bl * 64 + ic)) << 12);
    const double* wc = &wl[ic * 9];
    #pragma unroll
    for (int kh = 0; kh < 3; kh++) {
      int ih = oh - 1 + kh;
      if ((unsigned)ih < 64u) {
        const double* rp = ip + (ih << 6);
        #pragma unroll
        for (int kw = 0; kw < 3; kw++) {
          int iw = ow - 1 + kw;
          if ((unsigned)iw < 64u) {
            double v = rp[iw];
            acc += (v > 0.0 ? v : 0.0) * wc[kh * 3 + kw];
          }
        }
      }
    }
  }
  t[idx] = acc;
}

// encoder res 1x1 (fp64), per quarter, in place: x += conv1x1(relu(t)) + bias
__global__ __launch_bounds__(256) void k_res1x1_d(const double* __restrict__ t,
                                                  const float* __restrict__ w,
                                                  const float* __restrict__ bias,
                                                  double* __restrict__ x) {
  int idx = blockIdx.x * 256 + threadIdx.x;
  int p = idx & 4095, oc = (idx >> 12) & 63, bl = idx >> 18;
  __shared__ double wl[64];
  if (threadIdx.x < 64) wl[threadIdx.x] = (double)w[oc * 64 + threadIdx.x];
  __syncthreads();
  double acc = (double)bias[oc];
  const double* tp = t + (((long)bl) << 18) + p;
  for (int ic = 0; ic < 64; ic++) {
    double v = tp[(long)ic << 12];
    acc += (v > 0.0 ? v : 0.0) * wl[ic];
  }
  x[idx] = x[idx] + acc;
}

// VQ replicating np's fp32 arithmetic:
//   z32 = fl32(z);  zz = np-pairwise fp32 sum of z32^2
//   dot = exact fp64, t = fl32(2*fl32(dot))
//   d2  = fl32( fl32(zz - t) + ee )   [no contraction — explicit intrinsics]
//   argmin strict < (first-min, np.argmin)
//   stream <- e_st = fl32( fl32(q - z32) + z32 );  loss += (z32-q)^2 (fp64 sum)
__global__ __launch_bounds__(256) void k_quant(double* __restrict__ z, const float* __restrict__ emb,
                                               const float* __restrict__ eesq,
                                               double* __restrict__ loss) {
  __shared__ float el[4096];   // 16 KB: 64 codes x 64 ch
  __shared__ float ees[64];
  int n = blockIdx.x * 256 + threadIdx.x;
  int p = n & 4095, b = n >> 12;
  double* zp = z + (((long)b) << 18) + p;
  float z32[64];
  #pragma unroll
  for (int c = 0; c < 64; c++) z32[c] = (float)zp[(long)c << 12];
  float sq[64];
  #pragma unroll
  for (int c = 0; c < 64; c++) sq[c] = __fmul_rn(z32[c], z32[c]);
  float zz = np_pairwise64(sq);

  float best = 3.4e38f; int bi = 0;
  for (int e0 = 0; e0 < 512; e0 += 64) {
    __syncthreads();
    for (int i = threadIdx.x; i < 4096; i += 256) el[i] = emb[(e0 << 6) + i];
    if (threadIdx.x < 64) ees[threadIdx.x] = eesq[e0 + threadIdx.x];
    __syncthreads();
    for (int e = 0; e < 64; e++) {
      const float* ep = &el[e << 6];
      double dot = 0.0;
      #pragma unroll 8
      for (int c = 0; c < 64; c++) dot = fma((double)z32[c], (double)ep[c], dot);
      float t = __fmul_rn(2.0f, (float)dot);
      float d2 = __fadd_rn(__fsub_rn(zz, t), ees[e]);
      if (d2 < best) { best = d2; bi = e0 + e; }  // strict <: first-min
    }
  }
  const float* ebp = emb + bi * 64;
  double l = 0.0;
  #pragma unroll
  for (int c = 0; c < 64; c++) {
    float ev = ebp[c];
    float est = __fadd_rn(__fsub_rn(ev, z32[c]), z32[c]);  // straight-through fwd
    zp[(long)c << 12] = (double)est;
    float dd = __fsub_rn(z32[c], ev);
    l += (double)dd * (double)dd;
  }
  #pragma unroll
  for (int o = 32; o; o >>= 1) l += __shfl_down(l, o, 64);
  if ((threadIdx.x & 63) == 0) atomicAdd(loss, l);
}

// decoder res 3x3 (fp32 math, fp64-slot stream), per quarter
__global__ __launch_bounds__(256) void k_res3x3_f(const double* __restrict__ in,
                                                  const float* __restrict__ w,
                                                  const float* __restrict__ bias,
                                                  float* __restrict__ t) {
  int idx = blockIdx.x * 256 + threadIdx.x;
  int ow = idx & 63, oh = (idx >> 6) & 63, oc = (idx >> 12) & 63, bl = idx >> 18;
  __shared__ float wl[576];
  const float* wp = w + oc * 576;
  for (int i = threadIdx.x; i < 576; i += 256) wl[i] = wp[i];
  __syncthreads();
  float acc = bias[oc];
  for (int ic = 0; ic < 64; ic++) {
    const double* ip = in + (((long)(bl * 64 + ic)) << 12);
    const float* wc = &wl[ic * 9];
    #pragma unroll
    for (int kh = 0; kh < 3; kh++) {
      int ih = oh - 1 + kh;
      if ((unsigned)ih < 64u) {
        const double* rp = ip + (ih << 6);
        #pragma unroll
        for (int kw = 0; kw < 3; kw++) {
          int iw = ow - 1 + kw;
          if ((unsigned)iw < 64u) acc += fmaxf((float)rp[iw], 0.f) * wc[kh * 3 + kw];
        }
      }
    }
  }
  t[idx] = acc;
}

// decoder res 1x1 (fp32 math), per quarter, in place on fp64-slot stream
__global__ __launch_bounds__(256) void k_res1x1_f(const float* __restrict__ t,
                                                  const float* __restrict__ w,
                                                  const float* __restrict__ bias,
                                                  double* __restrict__ x) {
  int idx = blockIdx.x * 256 + threadIdx.x;
  int p = idx & 4095, oc = (idx >> 12) & 63, bl = idx >> 18;
  __shared__ float wl[64];
  if (threadIdx.x < 64) wl[threadIdx.x] = w[oc * 64 + threadIdx.x];
  __syncthreads();
  float acc = bias[oc];
  const float* tp = t + (((long)bl) << 18) + p;
  for (int ic = 0; ic < 64; ic++) acc += fmaxf(tp[(long)ic << 12], 0.f) * wl[ic];
  x[idx] = (double)((float)x[idx] + acc);
}

// convT1 core (fp32): 64->64 k4 s2 p1; in = stream (64,64,64,64) fp64-slots
__device__ __forceinline__ float convT1_acc(const double* __restrict__ in, const float* wl,
                                            int b, int oh, int ow) {
  int nh = 0, hih[2], hkh[2];
  for (int kh = (oh + 1) & 1; kh < 4; kh += 2) {
    int ih = (oh + 1 - kh) >> 1;
    if ((unsigned)ih < 64u) { hih[nh] = ih; hkh[nh] = kh; nh++; }
  }
  int nw = 0, wiw[2], wkw[2];
  for (int kw = (ow + 1) & 1; kw < 4; kw += 2) {
    int iw = (ow + 1 - kw) >> 1;
    if ((unsigned)iw < 64u) { wiw[nw] = iw; wkw[nw] = kw; nw++; }
  }
  float acc = 0.f;
  for (int ic = 0; ic < 64; ic++) {
    const double* ip = in + (((long)(b * 64 + ic)) << 12);
    const float* wc = &wl[ic << 4];
    for (int a = 0; a < nh; a++) {
      const double* rp = ip + (hih[a] << 6);
      int kb = hkh[a] << 2;
      for (int c2 = 0; c2 < nw; c2++) acc += (float)rp[wiw[c2]] * wc[kb + wkw[c2]];
    }
  }
  return acc;
}

// pass 1: BN3 stats only. grid = 64*64*128*128/256, oc block-uniform
__global__ __launch_bounds__(256) void k_convT1_stats(const double* __restrict__ in,
                                                      const float* __restrict__ w,
                                                      double* __restrict__ stats) {
  int idx = blockIdx.x * 256 + threadIdx.x;
  int ow = idx & 127, oh = (idx >> 7) & 127, oc = (idx >> 14) & 63, b = idx >> 20;
  __shared__ float wl[1024];
  for (int i = threadIdx.x; i < 1024; i += 256) {
    int ic = i >> 4, k = i & 15;
    wl[i] = w[(((long)ic * 64 + oc) << 4) + k];
  }
  __syncthreads();
  float acc = convT1_acc(in, wl, b, oh, ow);
  block_stats_atomic((double)acc, (double)acc * (double)acc, &stats[256 + oc], &stats[320 + oc]);
}

// pass 2 (per sixteenth): convT1 + BN3 + ReLU -> U32s fp32. grid = 16384
__global__ __launch_bounds__(256) void k_convT1_store(const double* __restrict__ in,
                                                      const float* __restrict__ w,
                                                      const double* __restrict__ sc,
                                                      const double* __restrict__ sh,
                                                      float* __restrict__ u, int boff) {
  int idx = blockIdx.x * 256 + threadIdx.x;
  int ow = idx & 127, oh = (idx >> 7) & 127, oc = (idx >> 14) & 63, b = (idx >> 20) + boff;
  __shared__ float wl[1024];
  for (int i = threadIdx.x; i < 1024; i += 256) {
    int ic = i >> 4, k = i & 15;
    wl[i] = w[(((long)ic * 64 + oc) << 4) + k];
  }
  __syncthreads();
  float acc = convT1_acc(in, wl, b, oh, ow);
  float v = acc * (float)sc[oc] + (float)sh[oc];
  u[idx] = fmaxf(v, 0.f);
}

// convT2 + bias + tanh (per sixteenth): U32s (4,64,128,128) -> out sixteenth
__global__ __launch_bounds__(256) void k_convT2(const float* __restrict__ in,
                                                const float* __restrict__ w,
                                                const float* __restrict__ bias,
                                                float* __restrict__ out, long ooff) {
  int idx = blockIdx.x * 256 + threadIdx.x;
  int ow = idx & 255, oh = (idx >> 8) & 255;
  int t = idx >> 16;            // bl*3+oc in [0,12), block-uniform
  int oc = t % 3, bl = t / 3;
  __shared__ float wl[1024];
  for (int i = threadIdx.x; i < 1024; i += 256) {
    int ic = i >> 4, k = i & 15;
    wl[i] = w[(((long)ic * 3 + oc) << 4) + k];
  }
  __syncthreads();
  int nh = 0, hih[2], hkh[2];
  for (int kh = (oh + 1) & 1; kh < 4; kh += 2) {
    int ih = (oh + 1 - kh) >> 1;
    if ((unsigned)ih < 128u) { hih[nh] = ih; hkh[nh] = kh; nh++; }
  }
  int nw = 0, wiw[2], wkw[2];
  for (int kw = (ow + 1) & 1; kw < 4; kw += 2) {
    int iw = (ow + 1 - kw) >> 1;
    if ((unsigned)iw < 128u) { wiw[nw] = iw; wkw[nw] = kw; nw++; }
  }
  float acc = bias[oc];
  for (int ic = 0; ic < 64; ic++) {
    const float* ip = in + (((long)(bl * 64 + ic)) << 14);
    const float* wc = &wl[ic << 4];
    for (int a = 0; a < nh; a++) {
      const float* rp = ip + (hih[a] << 7);
      int kb = hkh[a] << 2;
      for (int c2 = 0; c2 < nw; c2++) acc += rp[wiw[c2]] * wc[kb + wkw[c2]];
    }
  }
  out[ooff + idx] = tanhf(acc);
}

__global__ void k_loss(const double* __restrict__ loss, float* __restrict__ out) {
  if (threadIdx.x == 0) {
    float m = (float)(loss[0] * (1.0 / 16777216.0));
    out[OUTPIX] = m;      // vq_loss
    out[OUTPIX + 1] = m;  // commitment_loss (BETA=1)
  }
}

extern "C" void kernel_launch(void* const* d_in, const int* in_sizes, int n_in,
                              void* d_out, int out_size, void* d_ws, size_t ws_size,
                              hipStream_t stream) {
  (void)in_sizes; (void)n_in; (void)out_size; (void)ws_size;
  const float* x      = (const float*)d_in[0];
  const float* c1_w   = (const float*)d_in[1];
  const float* c1_g   = (const float*)d_in[2];
  const float* c1_b   = (const float*)d_in[3];
  const float* c2_w   = (const float*)d_in[4];
  const float* c2_g   = (const float*)d_in[5];
  const float* c2_b   = (const float*)d_in[6];
  const float* er1_w1 = (const float*)d_in[7];
  const float* er1_b1 = (const float*)d_in[8];
  const float* er1_w2 = (const float*)d_in[9];
  const float* er1_b2 = (const float*)d_in[10];
  const float* er2_w1 = (const float*)d_in[11];
  const float* er2_b1 = (const float*)d_in[12];
  const float* er2_w2 = (const float*)d_in[13];
  const float* er2_b2 = (const float*)d_in[14];
  const float* emb    = (const float*)d_in[15];
  const float* dr1_w1 = (const float*)d_in[16];
  const float* dr1_b1 = (const float*)d_in[17];
  const float* dr1_w2 = (const float*)d_in[18];
  const float* dr1_b2 = (const float*)d_in[19];
  const float* dr2_w1 = (const float*)d_in[20];
  const float* dr2_b1 = (const float*)d_in[21];
  const float* dr2_w2 = (const float*)d_in[22];
  const float* dr2_b2 = (const float*)d_in[23];
  const float* dt1_w  = (const float*)d_in[24];
  const float* dt1_g  = (const float*)d_in[25];
  const float* dt1_b  = (const float*)d_in[26];
  const float* dt2_w  = (const float*)d_in[27];
  const float* dt2_b  = (const float*)d_in[28];
  float* out = (float*)d_out;

  char* ws = (char*)d_ws;
  double* stats = (double*)ws;             // [0,3080)
  double* bnp   = (double*)(ws + 3584);    // 384 fp64
  double* sc1 = bnp,       *sh1 = bnp + 64;
  double* sc2 = bnp + 128, *sh2 = bnp + 192;
  double* sc3 = bnp + 256, *sh3 = bnp + 320;
  float*  ee    = (float*)(ws + 8192);     // 512 fp32
  char* A = ws + 16384;
  double* Z64 = (double*)A;                        // 128 Mi: z -> e_st -> stream
  char*   SB  = A + 134217728;                     // 32 Mi scratch
  double* A1s  = (double*)SB;                      // (4,64,128,128) fp64 = 32 Mi
  double* T64q = (double*)SB;                      // (16,64,64,64) fp64 = 32 Mi
  float*  T32q = (float*)SB;                       // (16,64,64,64) fp32 = 16 Mi
  float*  U32s = (float*)SB;                       // (4,64,128,128) fp32 = 16 Mi

  const int GB_FULL1 = 67108864 / 256;   // 262144  (64,64,128,128)
  const int GB_S1    = 4194304 / 256;    // 16384   (4,64,128,128)
  const int GB_S2    = 1048576 / 256;    // 4096    (4,64,64,64)
  const int GB_ZQ    = 4194304 / 256;    // 16384   (16,64,64,64)
  const int GB_Z     = 16777216 / 256;   // 65536   (64,64,64,64)
  const int GB_QU    = NPOS / 256;       // 1024
  const int GB_O16   = 786432 / 256;     // 3072    (4,3,256,256)

  k_zero<<<1, 512, 0, stream>>>(stats);
  k_ee<<<8, 64, 0, stream>>>(emb, ee);

  // encoder front-end (fp64): two-pass BN1, batch-sixteenth staging
  k_conv1_stats<<<GB_FULL1, 256, 0, stream>>>(x, c1_w, stats);
  k_finalize_bn<<<1, 64, 0, stream>>>(stats, stats + 64, c1_g, c1_b, sc1, sh1, 1.0 / 1048576.0);
  for (int s = 0; s < 16; s++) {
    k_conv1_store<<<GB_S1, 256, 0, stream>>>(x, c1_w, sc1, sh1, A1s, s * 4);
    k_conv2<<<GB_S2, 256, 0, stream>>>(A1s, c2_w, Z64 + (long)s * 1048576,
                                       stats + 128, stats + 192);
  }
  k_finalize_bn<<<1, 64, 0, stream>>>(stats + 128, stats + 192, c2_g, c2_b, sc2, sh2, 1.0 / 262144.0);
  k_bn_apply<<<GB_Z, 256, 0, stream>>>(Z64, sc2, sh2);

  // encoder resblocks (fp64), per batch-quarter with in-place residual
  for (int qr = 0; qr < 4; qr++) {
    double* zq = Z64 + (long)qr * 4194304;
    k_res3x3_d<<<GB_ZQ, 256, 0, stream>>>(zq, er1_w1, er1_b1, T64q);
    k_res1x1_d<<<GB_ZQ, 256, 0, stream>>>(T64q, er1_w2, er1_b2, zq);
  }
  for (int qr = 0; qr < 4; qr++) {
    double* zq = Z64 + (long)qr * 4194304;
    k_res3x3_d<<<GB_ZQ, 256, 0, stream>>>(zq, er2_w1, er2_b1, T64q);
    k_res1x1_d<<<GB_ZQ, 256, 0, stream>>>(T64q, er2_w2, er2_b2, zq);
  }

  // VQ (np-fp32-replicated distances), e_st overwrites Z64 in place
  k_quant<<<GB_QU, 256, 0, stream>>>(Z64, emb, ee, &stats[384]);

  // decoder resblocks (fp32 math on fp64-slot stream), per quarter
  for (int qr = 0; qr < 4; qr++) {
    double* sq = Z64 + (long)qr * 4194304;
    k_res3x3_f<<<GB_ZQ, 256, 0, stream>>>(sq, dr1_w1, dr1_b1, T32q);
    k_res1x1_f<<<GB_ZQ, 256, 0, stream>>>(T32q, dr1_w2, dr1_b2, sq);
  }
  for (int qr = 0; qr < 4; qr++) {
    double* sq = Z64 + (long)qr * 4194304;
    k_res3x3_f<<<GB_ZQ, 256, 0, stream>>>(sq, dr2_w1, dr2_b1, T32q);
    k_res1x1_f<<<GB_ZQ, 256, 0, stream>>>(T32q, dr2_w2, dr2_b2, sq);
  }

  // decoder tail: two-pass convT1+BN3 (sixteenths), then convT2+tanh
  k_convT1_stats<<<GB_FULL1, 256, 0, stream>>>(Z64, dt1_w, stats);
  k_finalize_bn<<<1, 64, 0, stream>>>(stats + 256, stats + 320, dt1_g, dt1_b, sc3, sh3, 1.0 / 1048576.0);
  for (int s = 0; s < 16; s++) {
    k_convT1_store<<<GB_S1, 256, 0, stream>>>(Z64, dt1_w, sc3, sh3, U32s, s * 4);
    k_convT2<<<GB_O16, 256, 0, stream>>>(U32s, dt2_w, dt2_b, out, (long)s * 786432);
  }

  k_loss<<<1, 64, 0, stream>>>(&stats[384], out);
}

// Round 7
// 47424.625 us; speedup vs baseline: 1.1707x; 1.1707x over previous
//
#include <hip/hip_runtime.h>
#include <hip/hip_bf16.h>
#include <math.h>

// ---------------------------------------------------------------------------
// VQ-VAE forward, MI355X. Round 7 = R6 (PASSING, 55.5ms) + convT optimization:
//  * convT1/convT2: parity-decomposed k4s2 transpose-conv — taps become a
//    compile-time 2x2 set with validity masks -> constant-trip unrolled loop
//    (R6's variable nh/nw loops blocked unrolling: 3.9 TF, 2.5% of peak).
//  * decoder stream is now f32-in-8B-slot ("f32s8"): quant/res/convT read and
//    write the float low half of each fp64 slot (same-slot => race-free,
//    bit-identical values, no cvt_f32_f64 in hot loops).
// Numerics recipe UNCHANGED (fp64 encoder/z, np-replicated fp32 d2, fp32
// decoder). Workspace high-water: 16384 + 160 MiB (proven).
// ---------------------------------------------------------------------------

#define NPOS   262144    // 64*64*64 z positions
#define OUTPIX 12582912  // 64*3*256*256

// block (256 thr) fp64 sum/sumsq reduce -> fp64 atomics.
__device__ __forceinline__ void block_stats_atomic(double s, double q,
                                                   double* sum_p, double* sq_p) {
  #pragma unroll
  for (int o = 32; o; o >>= 1) { s += __shfl_down(s, o, 64); q += __shfl_down(q, o, 64); }
  __shared__ double ls[4], lq[4];
  int lane = threadIdx.x & 63, wv = threadIdx.x >> 6;
  if (lane == 0) { ls[wv] = s; lq[wv] = q; }
  __syncthreads();
  if (threadIdx.x == 0) {
    atomicAdd(sum_p, ls[0] + ls[1] + ls[2] + ls[3]);
    atomicAdd(sq_p,  lq[0] + lq[1] + lq[2] + lq[3]);
  }
}

__global__ void k_zero(double* p) { if (threadIdx.x < 385) p[threadIdx.x] = 0.0; }

// numpy pairwise fp32 sum of 64 values (8 accumulators) — matches np n=64.
__device__ __forceinline__ float np_pairwise64(const float* sq) {
  float r[8];
  #pragma unroll
  for (int j = 0; j < 8; j++) r[j] = sq[j];
  #pragma unroll
  for (int i = 8; i < 64; i += 8)
    #pragma unroll
    for (int j = 0; j < 8; j++) r[j] = __fadd_rn(r[j], sq[i + j]);
  return __fadd_rn(__fadd_rn(__fadd_rn(r[0], r[1]), __fadd_rn(r[2], r[3])),
                   __fadd_rn(__fadd_rn(r[4], r[5]), __fadd_rn(r[6], r[7])));
}

// ee[e] = np-pairwise fp32 sum of emb[e,c]^2. <<<8,64>>>
__global__ void k_ee(const float* __restrict__ emb, float* __restrict__ ee) {
  int e = blockIdx.x * 64 + threadIdx.x;
  const float* p = emb + e * 64;
  float sq[64];
  #pragma unroll
  for (int c = 0; c < 64; c++) sq[c] = __fmul_rn(p[c], p[c]);
  ee[e] = np_pairwise64(sq);
}

// finalize BN (fp64): sc/sh per channel. <<<1,64>>>
__global__ void k_finalize_bn(const double* __restrict__ sums, const double* __restrict__ sqs,
                              const float* __restrict__ g, const float* __restrict__ bt,
                              double* __restrict__ sc, double* __restrict__ sh, double invN) {
  int c = threadIdx.x;
  double m = sums[c] * invN;
  double var = sqs[c] * invN - m * m;
  double s = (double)g[c] / sqrt(var + 1e-5);
  sc[c] = s;
  sh[c] = (double)bt[c] - m * s;
}

// conv1 core (fp64 acc): 3->64 k4 s2 p1, one output element
__device__ __forceinline__ double conv1_acc(const float* __restrict__ x, const float* wr,
                                            int b, int oh, int ow) {
  double acc = 0.0;
  int ih0 = oh * 2 - 1, iw0 = ow * 2 - 1;
  for (int ic = 0; ic < 3; ic++) {
    const float* ip = x + (((long)(b * 3 + ic)) << 16);
    #pragma unroll
    for (int kh = 0; kh < 4; kh++) {
      int ih = ih0 + kh;
      if ((unsigned)ih < 256u) {
        const float* rp = ip + (ih << 8);
        #pragma unroll
        for (int kw = 0; kw < 4; kw++) {
          int iw = iw0 + kw;
          if ((unsigned)iw < 256u)
            acc += (double)rp[iw] * (double)wr[(ic * 4 + kh) * 4 + kw];
        }
      }
    }
  }
  return acc;
}

// pass 1: BN1 stats only. grid = 64*64*128*128/256
__global__ __launch_bounds__(256) void k_conv1_stats(const float* __restrict__ x,
                                                     const float* __restrict__ w,
                                                     double* __restrict__ stats) {
  int idx = blockIdx.x * 256 + threadIdx.x;
  int ow = idx & 127, oh = (idx >> 7) & 127, oc = (idx >> 14) & 63, b = idx >> 20;
  float wr[48];
  const float* wp = w + oc * 48;
  #pragma unroll
  for (int i = 0; i < 48; i++) wr[i] = wp[i];
  double acc = conv1_acc(x, wr, b, oh, ow);
  block_stats_atomic(acc, acc * acc, &stats[oc], &stats[64 + oc]);
}

// pass 2 (per batch-sixteenth, 4 batches): conv1+BN1+ReLU -> A1s fp64. grid=16384
__global__ __launch_bounds__(256) void k_conv1_store(const float* __restrict__ x,
                                                     const float* __restrict__ w,
                                                     const double* __restrict__ sc,
                                                     const double* __restrict__ sh,
                                                     double* __restrict__ a1s, int boff) {
  int idx = blockIdx.x * 256 + threadIdx.x;
  int ow = idx & 127, oh = (idx >> 7) & 127, oc = (idx >> 14) & 63, b = (idx >> 20) + boff;
  float wr[48];
  const float* wp = w + oc * 48;
  #pragma unroll
  for (int i = 0; i < 48; i++) wr[i] = wp[i];
  double acc = conv1_acc(x, wr, b, oh, ow);
  double v = acc * sc[oc] + sh[oc];
  a1s[idx] = v > 0.0 ? v : 0.0;
}

// conv2 64->64 k4 s2 p1 (per sixteenth): A1s fp64 -> Z64, fused BN2 stats
__global__ __launch_bounds__(256) void k_conv2(const double* __restrict__ in,
                                               const float* __restrict__ w,
                                               double* __restrict__ out,
                                               double* __restrict__ sum_p, double* __restrict__ sq_p) {
  int idx = blockIdx.x * 256 + threadIdx.x;
  int ow = idx & 63, oh = (idx >> 6) & 63, oc = (idx >> 12) & 63, bl = idx >> 18;  // bl in [0,4)
  __shared__ double wl[1024];
  const float* wp = w + oc * 1024;
  for (int i = threadIdx.x; i < 1024; i += 256) wl[i] = (double)wp[i];
  __syncthreads();
  double acc = 0.0;
  int ih0 = oh * 2 - 1, iw0 = ow * 2 - 1;
  for (int ic = 0; ic < 64; ic++) {
    const double* ip = in + (((long)(bl * 64 + ic)) << 14);
    const double* wc = &wl[ic * 16];
    #pragma unroll
    for (int kh = 0; kh < 4; kh++) {
      int ih = ih0 + kh;
      if ((unsigned)ih < 128u) {
        const double* rp = ip + (ih << 7);
        #pragma unroll
        for (int kw = 0; kw < 4; kw++) {
          int iw = iw0 + kw;
          if ((unsigned)iw < 128u) acc += rp[iw] * wc[kh * 4 + kw];
        }
      }
    }
  }
  out[idx] = acc;
  block_stats_atomic(acc, acc * acc, &sum_p[oc], &sq_p[oc]);
}

// BN2 apply + ReLU in place on Z64. c=(idx>>12)&63
__global__ __launch_bounds__(256) void k_bn_apply(double* data, const double* __restrict__ sc,
                                                  const double* __restrict__ sh) {
  long idx = (long)blockIdx.x * 256 + threadIdx.x;
  int c = (int)((idx >> 12) & 63);
  double v = data[idx] * sc[c] + sh[c];
  data[idx] = v > 0.0 ? v : 0.0;
}

// encoder res 3x3 (fp64), per batch-quarter: T = conv3x3(relu(in)) + bias
__global__ __launch_bounds__(256) void k_res3x3_d(const double* __restrict__ in,
                                                  const float* __restrict__ w,
                                                  const float* __restrict__ bias,
                                                  double* __restrict__ t) {
  int idx = blockIdx.x * 256 + threadIdx.x;
  int ow = idx & 63, oh = (idx >> 6) & 63, oc = (idx >> 12) & 63, bl = idx >> 18; // [0,16)
  __shared__ double wl[576];
  const float* wp = w + oc * 576;
  for (int i = threadIdx.x; i < 576; i += 256) wl[i] = (double)wp[i];
  __syncthreads();
  double acc = (double)bias[oc];
  for (int ic = 0; ic < 64; ic++) {
    const double* ip = in + (((long)(bl * 64 + ic)) << 12);
    const double* wc = &wl[ic * 9];
    #pragma unroll
    for (int kh = 0; kh < 3; kh++) {
      int ih = oh - 1 + kh;
      if ((unsigned)ih < 64u) {
        const double* rp = ip + (ih << 6);
        #pragma unroll
        for (int kw = 0; kw < 3; kw++) {
          int iw = ow - 1 + kw;
          if ((unsigned)iw < 64u) {
            double v = rp[iw];
            acc += (v > 0.0 ? v : 0.0) * wc[kh * 3 + kw];
          }
        }
      }
    }
  }
  t[idx] = acc;
}

// encoder res 1x1 (fp64), per quarter, in place: x += conv1x1(relu(t)) + bias
__global__ __launch_bounds__(256) void k_res1x1_d(const double* __restrict__ t,
                                                  const float* __restrict__ w,
                                                  const float* __restrict__ bias,
                                                  double* __restrict__ x) {
  int idx = blockIdx.x * 256 + threadIdx.x;
  int p = idx & 4095, oc = (idx >> 12) & 63, bl = idx >> 18;
  __shared__ double wl[64];
  if (threadIdx.x < 64) wl[threadIdx.x] = (double)w[oc * 64 + threadIdx.x];
  __syncthreads();
  double acc = (double)bias[oc];
  const double* tp = t + (((long)bl) << 18) + p;
  for (int ic = 0; ic < 64; ic++) {
    double v = tp[(long)ic << 12];
    acc += (v > 0.0 ? v : 0.0) * wl[ic];
  }
  x[idx] = x[idx] + acc;
}

// VQ replicating np's fp32 arithmetic (R6-proven):
//   d2 = fl32( fl32(zz - 2*fl32(dot64)) + ee ), strict-< argmin.
//   Writes e_st = fl32(fl32(q - z32) + z32) as FLOAT into the low half of the
//   owned 8-byte slot (f32s8 decoder stream).
__global__ __launch_bounds__(256) void k_quant(double* __restrict__ z, const float* __restrict__ emb,
                                               const float* __restrict__ eesq,
                                               double* __restrict__ loss) {
  __shared__ float el[4096];   // 16 KB: 64 codes x 64 ch
  __shared__ float ees[64];
  int n = blockIdx.x * 256 + threadIdx.x;
  int p = n & 4095, b = n >> 12;
  double* zp = z + (((long)b) << 18) + p;
  float z32[64];
  #pragma unroll
  for (int c = 0; c < 64; c++) z32[c] = (float)zp[(long)c << 12];
  float sq[64];
  #pragma unroll
  for (int c = 0; c < 64; c++) sq[c] = __fmul_rn(z32[c], z32[c]);
  float zz = np_pairwise64(sq);

  float best = 3.4e38f; int bi = 0;
  for (int e0 = 0; e0 < 512; e0 += 64) {
    __syncthreads();
    for (int i = threadIdx.x; i < 4096; i += 256) el[i] = emb[(e0 << 6) + i];
    if (threadIdx.x < 64) ees[threadIdx.x] = eesq[e0 + threadIdx.x];
    __syncthreads();
    for (int e = 0; e < 64; e++) {
      const float* ep = &el[e << 6];
      double dot = 0.0;
      #pragma unroll 8
      for (int c = 0; c < 64; c++) dot = fma((double)z32[c], (double)ep[c], dot);
      float t = __fmul_rn(2.0f, (float)dot);
      float d2 = __fadd_rn(__fsub_rn(zz, t), ees[e]);
      if (d2 < best) { best = d2; bi = e0 + e; }  // strict <: first-min
    }
  }
  const float* ebp = emb + bi * 64;
  float* fzp = (float*)zp;
  double l = 0.0;
  #pragma unroll
  for (int c = 0; c < 64; c++) {
    float ev = ebp[c];
    float est = __fadd_rn(__fsub_rn(ev, z32[c]), z32[c]);  // straight-through fwd
    fzp[(long)c << 13] = est;                              // f32s8 store
    float dd = __fsub_rn(z32[c], ev);
    l += (double)dd * (double)dd;
  }
  #pragma unroll
  for (int o = 32; o; o >>= 1) l += __shfl_down(l, o, 64);
  if ((threadIdx.x & 63) == 0) atomicAdd(loss, l);
}

// decoder res 3x3 (fp32), per quarter; stream input is f32s8 (stride-2 floats)
__global__ __launch_bounds__(256) void k_res3x3_f(const double* __restrict__ in,
                                                  const float* __restrict__ w,
                                                  const float* __restrict__ bias,
                                                  float* __restrict__ t) {
  int idx = blockIdx.x * 256 + threadIdx.x;
  int ow = idx & 63, oh = (idx >> 6) & 63, oc = (idx >> 12) & 63, bl = idx >> 18;
  __shared__ float wl[576];
  const float* wp = w + oc * 576;
  for (int i = threadIdx.x; i < 576; i += 256) wl[i] = wp[i];
  __syncthreads();
  const float* inf = (const float*)in;
  float acc = bias[oc];
  for (int ic = 0; ic < 64; ic++) {
    const float* ip = inf + (((long)(bl * 64 + ic)) << 13);
    const float* wc = &wl[ic * 9];
    #pragma unroll
    for (int kh = 0; kh < 3; kh++) {
      int ih = oh - 1 + kh;
      if ((unsigned)ih < 64u) {
        const float* rp = ip + (ih << 7);
        #pragma unroll
        for (int kw = 0; kw < 3; kw++) {
          int iw = ow - 1 + kw;
          if ((unsigned)iw < 64u) acc += fmaxf(rp[iw << 1], 0.f) * wc[kh * 3 + kw];
        }
      }
    }
  }
  t[idx] = acc;
}

// decoder res 1x1 (fp32), per quarter, in place on f32s8 stream
__global__ __launch_bounds__(256) void k_res1x1_f(const float* __restrict__ t,
                                                  const float* __restrict__ w,
                                                  const float* __restrict__ bias,
                                                  double* __restrict__ x) {
  int idx = blockIdx.x * 256 + threadIdx.x;
  int p = idx & 4095, oc = (idx >> 12) & 63, bl = idx >> 18;
  __shared__ float wl[64];
  if (threadIdx.x < 64) wl[threadIdx.x] = w[oc * 64 + threadIdx.x];
  __syncthreads();
  float acc = bias[oc];
  const float* tp = t + (((long)bl) << 18) + p;
  for (int ic = 0; ic < 64; ic++) acc += fmaxf(tp[(long)ic << 12], 0.f) * wl[ic];
  float* xf = (float*)x;
  long fi = (long)idx << 1;
  xf[fi] = xf[fi] + acc;
}

// convT1 core, parity-decomposed: 64->64 k4 s2 p1 on f32s8 stream.
// For output (oh,ow): kh in {ph, ph+2}, ih in {ih0, ih0-1}; same for w.
// Constant-trip 2x2 taps with validity masks -> fully unrolled.
__device__ __forceinline__ float convT1_acc(const float* __restrict__ inf, const float* wl,
                                            int b, int oh, int ow) {
  int ph = (oh + 1) & 1, pw = (ow + 1) & 1;
  int ih0 = (oh + 1 - ph) >> 1, iw0 = (ow + 1 - pw) >> 1;
  int ih1 = ih0 - 1, iw1 = iw0 - 1;
  bool vh0 = ih0 < 64, vh1 = ih1 >= 0, vw0 = iw0 < 64, vw1 = iw1 >= 0;
  int ch0 = vh0 ? ih0 : 0, ch1 = vh1 ? ih1 : 0;
  int cw0 = vw0 ? iw0 : 0, cw1 = vw1 ? iw1 : 0;
  int o00 = (ch0 << 7) + (cw0 << 1), o01 = (ch0 << 7) + (cw1 << 1);
  int o10 = (ch1 << 7) + (cw0 << 1), o11 = (ch1 << 7) + (cw1 << 1);
  bool m00 = vh0 && vw0, m01 = vh0 && vw1, m10 = vh1 && vw0, m11 = vh1 && vw1;
  int wA = ph * 4 + pw, wB = wA + 2, wC = wA + 8, wD = wA + 10;
  float acc = 0.f;
  const float* ip = inf + (((long)b) << 19);   // 64 planes * 8192 floats
  #pragma unroll 8
  for (int ic = 0; ic < 64; ic++) {
    const float* pp = ip + ((long)ic << 13);
    const float* wc = &wl[ic << 4];
    float v00 = m00 ? pp[o00] : 0.f;
    float v01 = m01 ? pp[o01] : 0.f;
    float v10 = m10 ? pp[o10] : 0.f;
    float v11 = m11 ? pp[o11] : 0.f;
    acc += v00 * wc[wA] + v01 * wc[wB] + v10 * wc[wC] + v11 * wc[wD];
  }
  return acc;
}

// pass 1: BN3 stats only. grid = 64*64*128*128/256, oc block-uniform
__global__ __launch_bounds__(256) void k_convT1_stats(const float* __restrict__ inf,
                                                      const float* __restrict__ w,
                                                      double* __restrict__ stats) {
  int idx = blockIdx.x * 256 + threadIdx.x;
  int ow = idx & 127, oh = (idx >> 7) & 127, oc = (idx >> 14) & 63, b = idx >> 20;
  __shared__ float wl[1024];
  for (int i = threadIdx.x; i < 1024; i += 256) {
    int ic = i >> 4, k = i & 15;
    wl[i] = w[(((long)ic * 64 + oc) << 4) + k];
  }
  __syncthreads();
  float acc = convT1_acc(inf, wl, b, oh, ow);
  block_stats_atomic((double)acc, (double)acc * (double)acc, &stats[256 + oc], &stats[320 + oc]);
}

// pass 2 (per sixteenth): convT1 + BN3 + ReLU -> U32s fp32. grid = 16384
__global__ __launch_bounds__(256) void k_convT1_store(const float* __restrict__ inf,
                                                      const float* __restrict__ w,
                                                      const double* __restrict__ sc,
                                                      const double* __restrict__ sh,
                                                      float* __restrict__ u, int boff) {
  int idx = blockIdx.x * 256 + threadIdx.x;
  int ow = idx & 127, oh = (idx >> 7) & 127, oc = (idx >> 14) & 63, b = (idx >> 20) + boff;
  __shared__ float wl[1024];
  for (int i = threadIdx.x; i < 1024; i += 256) {
    int ic = i >> 4, k = i & 15;
    wl[i] = w[(((long)ic * 64 + oc) << 4) + k];
  }
  __syncthreads();
  float acc = convT1_acc(inf, wl, b, oh, ow);
  float v = acc * (float)sc[oc] + (float)sh[oc];
  u[idx] = fmaxf(v, 0.f);
}

// convT2 + bias + tanh (per sixteenth), parity-decomposed.
// U32s (4,64,128,128) dense fp32 -> out sixteenth (4,3,256,256)
__global__ __launch_bounds__(256) void k_convT2(const float* __restrict__ in,
                                                const float* __restrict__ w,
                                                const float* __restrict__ bias,
                                                float* __restrict__ out, long ooff) {
  int idx = blockIdx.x * 256 + threadIdx.x;
  int ow = idx & 255, oh = (idx >> 8) & 255;
  int t = idx >> 16;            // bl*3+oc in [0,12), block-uniform
  int oc = t % 3, bl = t / 3;
  __shared__ float wl[1024];
  for (int i = threadIdx.x; i < 1024; i += 256) {
    int ic = i >> 4, k = i & 15;
    wl[i] = w[(((long)ic * 3 + oc) << 4) + k];
  }
  __syncthreads();
  int ph = (oh + 1) & 1, pw = (ow + 1) & 1;
  int ih0 = (oh + 1 - ph) >> 1, iw0 = (ow + 1 - pw) >> 1;
  int ih1 = ih0 - 1, iw1 = iw0 - 1;
  bool vh0 = ih0 < 128, vh1 = ih1 >= 0, vw0 = iw0 < 128, vw1 = iw1 >= 0;
  int ch0 = vh0 ? ih0 : 0, ch1 = vh1 ? ih1 : 0;
  int cw0 = vw0 ? iw0 : 0, cw1 = vw1 ? iw1 : 0;
  int o00 = (ch0 << 7) + cw0, o01 = (ch0 << 7) + cw1;
  int o10 = (ch1 << 7) + cw0, o11 = (ch1 << 7) + cw1;
  bool m00 = vh0 && vw0, m01 = vh0 && vw1, m10 = vh1 && vw0, m11 = vh1 && vw1;
  int wA = ph * 4 + pw, wB = wA + 2, wC = wA + 8, wD = wA + 10;
  float acc = bias[oc];
  const float* ip = in + (((long)bl) << 20);  // 64 planes * 16384 floats
  #pragma unroll 8
  for (int ic = 0; ic < 64; ic++) {
    const float* pp = ip + ((long)ic << 14);
    const float* wc = &wl[ic << 4];
    float v00 = m00 ? pp[o00] : 0.f;
    float v01 = m01 ? pp[o01] : 0.f;
    float v10 = m10 ? pp[o10] : 0.f;
    float v11 = m11 ? pp[o11] : 0.f;
    acc += v00 * wc[wA] + v01 * wc[wB] + v10 * wc[wC] + v11 * wc[wD];
  }
  out[ooff + idx] = tanhf(acc);
}

__global__ void k_loss(const double* __restrict__ loss, float* __restrict__ out) {
  if (threadIdx.x == 0) {
    float m = (float)(loss[0] * (1.0 / 16777216.0));
    out[OUTPIX] = m;      // vq_loss
    out[OUTPIX + 1] = m;  // commitment_loss (BETA=1)
  }
}

extern "C" void kernel_launch(void* const* d_in, const int* in_sizes, int n_in,
                              void* d_out, int out_size, void* d_ws, size_t ws_size,
                              hipStream_t stream) {
  (void)in_sizes; (void)n_in; (void)out_size; (void)ws_size;
  const float* x      = (const float*)d_in[0];
  const float* c1_w   = (const float*)d_in[1];
  const float* c1_g   = (const float*)d_in[2];
  const float* c1_b   = (const float*)d_in[3];
  const float* c2_w   = (const float*)d_in[4];
  const float* c2_g   = (const float*)d_in[5];
  const float* c2_b   = (const float*)d_in[6];
  const float* er1_w1 = (const float*)d_in[7];
  const float* er1_b1 = (const float*)d_in[8];
  const float* er1_w2 = (const float*)d_in[9];
  const float* er1_b2 = (const float*)d_in[10];
  const float* er2_w1 = (const float*)d_in[11];
  const float* er2_b1 = (const float*)d_in[12];
  const float* er2_w2 = (const float*)d_in[13];
  const float* er2_b2 = (const float*)d_in[14];
  const float* emb    = (const float*)d_in[15];
  const float* dr1_w1 = (const float*)d_in[16];
  const float* dr1_b1 = (const float*)d_in[17];
  const float* dr1_w2 = (const float*)d_in[18];
  const float* dr1_b2 = (const float*)d_in[19];
  const float* dr2_w1 = (const float*)d_in[20];
  const float* dr2_b1 = (const float*)d_in[21];
  const float* dr2_w2 = (const float*)d_in[22];
  const float* dr2_b2 = (const float*)d_in[23];
  const float* dt1_w  = (const float*)d_in[24];
  const float* dt1_g  = (const float*)d_in[25];
  const float* dt1_b  = (const float*)d_in[26];
  const float* dt2_w  = (const float*)d_in[27];
  const float* dt2_b  = (const float*)d_in[28];
  float* out = (float*)d_out;

  char* ws = (char*)d_ws;
  double* stats = (double*)ws;             // [0,3080)
  double* bnp   = (double*)(ws + 3584);    // 384 fp64
  double* sc1 = bnp,       *sh1 = bnp + 64;
  double* sc2 = bnp + 128, *sh2 = bnp + 192;
  double* sc3 = bnp + 256, *sh3 = bnp + 320;
  float*  ee    = (float*)(ws + 8192);     // 512 fp32
  char* A = ws + 16384;
  double* Z64 = (double*)A;                        // 128 Mi: z -> f32s8 stream
  char*   SB  = A + 134217728;                     // 32 Mi scratch
  double* A1s  = (double*)SB;                      // (4,64,128,128) fp64 = 32 Mi
  double* T64q = (double*)SB;                      // (16,64,64,64) fp64 = 32 Mi
  float*  T32q = (float*)SB;                       // (16,64,64,64) fp32 = 16 Mi
  float*  U32s = (float*)SB;                       // (4,64,128,128) fp32 = 16 Mi

  const int GB_FULL1 = 67108864 / 256;   // 262144  (64,64,128,128)
  const int GB_S1    = 4194304 / 256;    // 16384   (4,64,128,128)
  const int GB_S2    = 1048576 / 256;    // 4096    (4,64,64,64)
  const int GB_ZQ    = 4194304 / 256;    // 16384   (16,64,64,64)
  const int GB_Z     = 16777216 / 256;   // 65536   (64,64,64,64)
  const int GB_QU    = NPOS / 256;       // 1024
  const int GB_O16   = 786432 / 256;     // 3072    (4,3,256,256)

  k_zero<<<1, 512, 0, stream>>>(stats);
  k_ee<<<8, 64, 0, stream>>>(emb, ee);

  // encoder front-end (fp64): two-pass BN1, batch-sixteenth staging
  k_conv1_stats<<<GB_FULL1, 256, 0, stream>>>(x, c1_w, stats);
  k_finalize_bn<<<1, 64, 0, stream>>>(stats, stats + 64, c1_g, c1_b, sc1, sh1, 1.0 / 1048576.0);
  for (int s = 0; s < 16; s++) {
    k_conv1_store<<<GB_S1, 256, 0, stream>>>(x, c1_w, sc1, sh1, A1s, s * 4);
    k_conv2<<<GB_S2, 256, 0, stream>>>(A1s, c2_w, Z64 + (long)s * 1048576,
                                       stats + 128, stats + 192);
  }
  k_finalize_bn<<<1, 64, 0, stream>>>(stats + 128, stats + 192, c2_g, c2_b, sc2, sh2, 1.0 / 262144.0);
  k_bn_apply<<<GB_Z, 256, 0, stream>>>(Z64, sc2, sh2);

  // encoder resblocks (fp64), per batch-quarter with in-place residual
  for (int qr = 0; qr < 4; qr++) {
    double* zq = Z64 + (long)qr * 4194304;
    k_res3x3_d<<<GB_ZQ, 256, 0, stream>>>(zq, er1_w1, er1_b1, T64q);
    k_res1x1_d<<<GB_ZQ, 256, 0, stream>>>(T64q, er1_w2, er1_b2, zq);
  }
  for (int qr = 0; qr < 4; qr++) {
    double* zq = Z64 + (long)qr * 4194304;
    k_res3x3_d<<<GB_ZQ, 256, 0, stream>>>(zq, er2_w1, er2_b1, T64q);
    k_res1x1_d<<<GB_ZQ, 256, 0, stream>>>(T64q, er2_w2, er2_b2, zq);
  }

  // VQ (np-fp32-replicated distances), e_st -> f32s8 stream in Z64
  k_quant<<<GB_QU, 256, 0, stream>>>(Z64, emb, ee, &stats[384]);

  // decoder resblocks (fp32 on f32s8 stream), per quarter
  for (int qr = 0; qr < 4; qr++) {
    double* sq = Z64 + (long)qr * 4194304;
    k_res3x3_f<<<GB_ZQ, 256, 0, stream>>>(sq, dr1_w1, dr1_b1, T32q);
    k_res1x1_f<<<GB_ZQ, 256, 0, stream>>>(T32q, dr1_w2, dr1_b2, sq);
  }
  for (int qr = 0; qr < 4; qr++) {
    double* sq = Z64 + (long)qr * 4194304;
    k_res3x3_f<<<GB_ZQ, 256, 0, stream>>>(sq, dr2_w1, dr2_b1, T32q);
    k_res1x1_f<<<GB_ZQ, 256, 0, stream>>>(T32q, dr2_w2, dr2_b2, sq);
  }

  // decoder tail: two-pass convT1+BN3 (sixteenths), then convT2+tanh
  k_convT1_stats<<<GB_FULL1, 256, 0, stream>>>((const float*)Z64, dt1_w, stats);
  k_finalize_bn<<<1, 64, 0, stream>>>(stats + 256, stats + 320, dt1_g, dt1_b, sc3, sh3, 1.0 / 1048576.0);
  for (int s = 0; s < 16; s++) {
    k_convT1_store<<<GB_S1, 256, 0, stream>>>((const float*)Z64, dt1_w, sc3, sh3, U32s, s * 4);
    k_convT2<<<GB_O16, 256, 0, stream>>>(U32s, dt2_w, dt2_b, out, (long)s * 786432);
  }

  k_loss<<<1, 64, 0, stream>>>(&stats[384], out);
}